// Round 7
// baseline (194.249 us; speedup 1.0000x reference)
//
#include <hip/hip_runtime.h>
#include <hip/hip_bf16.h>
#include <stdint.h>

// Problem constants (B=16, S=1024, E=8 qubits -> 2^8 = 256 amplitudes).
#define NB 16
#define S_LEN 1024
#define E_Q 8

typedef float v4f __attribute__((ext_vector_type(4)));
typedef short v8s __attribute__((ext_vector_type(8)));
typedef int   v4i __attribute__((ext_vector_type(4)));

// ---------------------------------------------------------------------------
// Kernel 1: per-token cos/sin feature tables, INT8 (scale 127).
//   L = sum_i x_i s_i,  phi = -0.5 L - 0.25 (L^2 - ||x||^2),  s_i=(-1)^{z_i}
// Q-table row (512 B): [round(127 cos phi) | round(127 sin phi)]
// K-table row (768 B): [127 cos | 127 sin | -127 cos]  (third window feeds
//   the Im chain: Im = cq.sk + sq.(-ck)).
// Gray-code walk of the low nibble: one fma per z.
// Side job: first 128 blocks of the which==0 half zero d_out (exactly
// 32768 float4 == 131072 floats).
// ---------------------------------------------------------------------------
__global__ __launch_bounds__(256) void build_tables(
    const float* __restrict__ Q, const float* __restrict__ K,
    int8_t* __restrict__ Aq, int8_t* __restrict__ Kt,
    float* __restrict__ out)
{
    const int which = blockIdx.y;
    const float* X = which ? K : Q;

    if (which == 0 && blockIdx.x < 128) {   // zero d_out: 128*256 float4
        float4 z; z.x = z.y = z.z = z.w = 0.f;
        ((float4*)out)[blockIdx.x * 256 + threadIdx.x] = z;
    }

    const int tok = blockIdx.x * 16 + (threadIdx.x >> 4);
    const int hi  = threadIdx.x & 15;     // z bits 4..7
    const int zb  = hi * 16;

    const float* x = X + tok * E_Q;
    float xv[E_Q]; float sq = 0.f;
#pragma unroll
    for (int i = 0; i < E_Q; ++i) { xv[i] = x[i]; sq += xv[i] * xv[i]; }
    const float qsq = 0.25f * sq;

    // L at z = zb: low 4 bits 0 (sign +), high bits from `hi`.
    float L = xv[0] + xv[1] + xv[2] + xv[3];
#pragma unroll
    for (int i = 4; i < 8; ++i) L += ((hi >> (i - 4)) & 1) ? -xv[i] : xv[i];

    __align__(16) int8_t cb[16];
    __align__(16) int8_t sb[16];

    {   // n = 0, gray = 0
        const float phi = fmaf(-0.25f, L * L, fmaf(-0.5f, L, qsq));
        float s, c; __sincosf(phi, &s, &c);
        cb[0] = (int8_t)__float2int_rn(127.f * c);
        sb[0] = (int8_t)__float2int_rn(127.f * s);
    }
#pragma unroll
    for (int n = 1; n < 16; ++n) {
        const int g  = n ^ (n >> 1);
        const int gp = (n - 1) ^ ((n - 1) >> 1);
        const int t  = __builtin_ctz(g ^ gp);        // constant-folds
        const float twox = 2.0f * xv[t];
        L = ((g >> t) & 1) ? (L - twox) : (L + twox);
        const float phi = fmaf(-0.25f, L * L, fmaf(-0.5f, L, qsq));
        float s, c; __sincosf(phi, &s, &c);
        cb[g] = (int8_t)__float2int_rn(127.f * c);
        sb[g] = (int8_t)__float2int_rn(127.f * s);
    }

    if (which == 0) {
        int8_t* dst = Aq + (size_t)tok * 512;
        *(uint4*)(dst + zb)       = *(const uint4*)cb;
        *(uint4*)(dst + 256 + zb) = *(const uint4*)sb;
    } else {
        __align__(16) int8_t nb[16];
#pragma unroll
        for (int i = 0; i < 16; ++i) nb[i] = (int8_t)(-cb[i]);
        int8_t* dst = Kt + (size_t)tok * 768;
        *(uint4*)(dst + zb)       = *(const uint4*)cb;
        *(uint4*)(dst + 256 + zb) = *(const uint4*)sb;
        *(uint4*)(dst + 512 + zb) = *(const uint4*)nb;
    }
}

// ---------------------------------------------------------------------------
// Kernel 2: fused QK fidelity GEMM (i8) + nonlinearity + MFMA PV + atomics.
// R7 restructure: 512-thread blocks, 256(i) x 128(j) tile -> grid is exactly
// 512 blocks = 2/CU: the WHOLE grid is co-resident in one generation at
// 16 waves/CU (vs 2048 blocks / 4 generations / ~17% occupancy before).
// Per c-iter (c=0..3) stage (64 KB):
//   lA  [256][128B] <- Q-chunk c of [cq|sq]      (row stride 512)
//   lK0 [128][128B] <- K-chunk c of [ck|sk|-ck]  (row stride 768) -> Re
//   lK1 [128][128B] <- K-chunk c+2               -> Im
// 8 waves in a 4(i) x 2(j) quadrant grid of 64x64; per-wave structure,
// XOR chunk swizzle (slot = q ^ (row&7)), C^T-trick epilogue (packed b64
// attn stores), MFMA PV and f32 atomicAdd are unchanged from R6.
// Epilogue aliases: lattn [256][136] bf16 (69632 B) + lVt [16][136] bf16.
// ---------------------------------------------------------------------------
__global__ __launch_bounds__(512, 4) void qk_pv(
    const int8_t* __restrict__ Aq, const int8_t* __restrict__ Kt,
    const float* __restrict__ V, float* __restrict__ out)
{
    __shared__ __align__(16) char smem[73984];
    int8_t* lA  = (int8_t*)smem;                    // [256][128] i8 (Q side)
    int8_t* lK0 = (int8_t*)(smem + 32768);          // [128][128] i8
    int8_t* lK1 = (int8_t*)(smem + 49152);          // [128][128] i8
    // phase-2 aliases (valid after the post-K-loop barrier)
    uint16_t* lattn = (uint16_t*)smem;              // [256][136] bf16, rows=i
    uint16_t* lVt   = (uint16_t*)(smem + 69632);    // [16][136]  bf16 (V^T)

    const int jblk = blockIdx.x, iblk = blockIdx.y, b = blockIdx.z;
    const int tid  = threadIdx.x;
    const int lane = tid & 63, wv = tid >> 6;       // wv in [0,8)
    const int wQi = wv >> 1, wKj = wv & 1;          // 4(i) x 2(j) quadrants
    const int r15 = lane & 15, qq = lane >> 4;

    // Staging maps. lA: 2048 chunks, 4/thread (f = p*512 + tid); lK: 1024
    // chunks per tile, 2/thread. Chunk f -> LDS byte f*16 (wave-uniform
    // base p*8192 + wv*1024); source row r = f>>3, physical slot f&7 holds
    // logical chunk (f&7)^(r&7).
    int goffA[4], goffK[2];
#pragma unroll
    for (int p = 0; p < 4; ++p) {
        const int f = p * 512 + tid;
        const int r = f >> 3, q = (f & 7) ^ (r & 7);
        goffA[p] = r * 512 + q * 16;
    }
#pragma unroll
    for (int p = 0; p < 2; ++p) {
        const int g = p * 512 + tid;
        const int r = g >> 3, q = (g & 7) ^ (r & 7);
        goffK[p] = r * 768 + q * 16;
    }
    const int lbase = wv * 1024;                     // wave-uniform LDS base

    const int8_t* gA = Aq + (size_t)(b * S_LEN + iblk * 256) * 512;
    const int8_t* gK = Kt + (size_t)(b * S_LEN + jblk * 128) * 768;

    // V tile load issued early (threads 0..255): V[b][jblk*128 + tid>>1][..]
    float4 vreg; vreg.x = vreg.y = vreg.z = vreg.w = 0.f;
    if (tid < 256)
        vreg = ((const float4*)(V + ((size_t)b * S_LEN + jblk * 128) * E_Q))[tid];

    v4i accRe[4][4], accIm[4][4];                    // [nj][mi]
#pragma unroll
    for (int nj = 0; nj < 4; ++nj)
#pragma unroll
        for (int mi = 0; mi < 4; ++mi) {
            accRe[nj][mi] = (v4i)0;
            accIm[nj][mi] = (v4i)0;
        }

    for (int c = 0; c < 4; ++c) {
        __syncthreads();                             // LDS safe to overwrite
        const int cbyte = c * 128;
#pragma unroll
        for (int p = 0; p < 4; ++p)
            __builtin_amdgcn_global_load_lds(
                (const __attribute__((address_space(1))) void*)(gA + cbyte + goffA[p]),
                (__attribute__((address_space(3))) void*)(lA + p * 8192 + lbase), 16, 0, 0);
#pragma unroll
        for (int p = 0; p < 2; ++p) {
            __builtin_amdgcn_global_load_lds(
                (const __attribute__((address_space(1))) void*)(gK + cbyte + goffK[p]),
                (__attribute__((address_space(3))) void*)(lK0 + p * 8192 + lbase), 16, 0, 0);
            __builtin_amdgcn_global_load_lds(
                (const __attribute__((address_space(1))) void*)(gK + 256 + cbyte + goffK[p]),
                (__attribute__((address_space(3))) void*)(lK1 + p * 8192 + lbase), 16, 0, 0);
        }
        __syncthreads();                             // drain staging

#pragma unroll
        for (int w = 0; w < 2; ++w) {
            v4i qF[4];                               // B-operand (Q side)
#pragma unroll
            for (int mi = 0; mi < 4; ++mi) {
                const int row = wQi * 64 + mi * 16 + r15;          // [0,256)
                qF[mi] = *(const v4i*)&lA[row * 128 + (((w << 2) | qq) ^ (row & 7)) * 16];
            }
#pragma unroll
            for (int nj = 0; nj < 4; ++nj) {
                const int rk  = wKj * 64 + nj * 16 + r15;          // [0,128)
                const int off = rk * 128 + (((w << 2) | qq) ^ (rk & 7)) * 16;
                const v4i k0 = *(const v4i*)&lK0[off];   // A-operand (K side)
                const v4i k1 = *(const v4i*)&lK1[off];
#pragma unroll
                for (int mi = 0; mi < 4; ++mi) {
                    accRe[nj][mi] = __builtin_amdgcn_mfma_i32_16x16x64_i8(k0, qF[mi], accRe[nj][mi], 0, 0, 0);
                    accIm[nj][mi] = __builtin_amdgcn_mfma_i32_16x16x64_i8(k1, qF[mi], accIm[nj][mi], 0, 0, 0);
                }
            }
        }
    }

    // ---- Epilogue: attn -> LDS bf16 [i][136+j]; V^T -> LDS bf16 [16][136] ----
    __syncthreads();                                 // all frag reads done

    const float sc2 = 3.0517578125e-05f / 260144641.0f;   // 2^-15 / 127^4
    // C^T layout: D row = j = wKj*64 + nj*16 + qq*4 + rg,  col = i = wQi*64
    // + mi*16 + r15.  4 consecutive j at fixed i -> one packed b64 store.
#pragma unroll
    for (int nj = 0; nj < 4; ++nj) {
#pragma unroll
        for (int mi = 0; mi < 4; ++mi) {
            uint64_t pk = 0;
#pragma unroll
            for (int rg = 0; rg < 4; ++rg) {
                const float rf  = (float)accRe[nj][mi][rg];
                const float imf = (float)accIm[nj][mi][rg];
                const float a   = fmaf(rf * rf + imf * imf, sc2, -1.0f);
                __hip_bfloat16 ab = __float2bfloat16(a);
                pk |= (uint64_t)(*(const uint16_t*)&ab) << (16 * rg);
            }
            const int i  = wQi * 64 + mi * 16 + r15;   // [0,256)
            const int j0 = wKj * 64 + nj * 16 + qq * 4;
            *(uint64_t*)&lattn[i * 136 + j0] = pk;
        }
    }
    if (tid < 256) {   // V^T rows 0..7: lVt[e][j] = bf16(V[b][jblk*128+j][e])
        const int j = tid >> 1, eh = (tid & 1) * 4;
        const float vv[4] = {vreg.x, vreg.y, vreg.z, vreg.w};
#pragma unroll
        for (int c2 = 0; c2 < 4; ++c2) {
            __hip_bfloat16 vb = __float2bfloat16(vv[c2]);
            lVt[(eh + c2) * 136 + j] = *(const uint16_t*)&vb;
        }
    } else {           // zero V^T rows 8..15 (uninitialized LDS in this layout)
        for (int k = tid - 256; k < 8 * 136; k += 256) lVt[8 * 136 + k] = 0;
    }
    __syncthreads();

    // ---- Phase 2: out-tile[256][8] = attnTile[256x128] @ Vt^T via MFMA ----
    v8s bfr[4];
#pragma unroll
    for (int ks3 = 0; ks3 < 4; ++ks3)
        bfr[ks3] = *(const v8s*)&lVt[r15 * 136 + ks3 * 32 + qq * 8];

    float* outb = out + (((size_t)b << 10) + iblk * 256) * E_Q;
#pragma unroll
    for (int mt = 0; mt < 2; ++mt) {
        const int rowbase = (wv * 2 + mt) * 16;      // [0,256) over 8 waves
        v4f accO = (v4f)0.f;
#pragma unroll
        for (int ks3 = 0; ks3 < 4; ++ks3) {
            const v8s af = *(const v8s*)&lattn[(rowbase + r15) * 136 + ks3 * 32 + qq * 8];
            accO = __builtin_amdgcn_mfma_f32_16x16x32_bf16(af, bfr[ks3], accO, 0, 0, 0);
        }
        if (r15 < E_Q) {
            const int i0 = rowbase + qq * 4;
#pragma unroll
            for (int rg = 0; rg < 4; ++rg)
                atomicAdd(&outb[(i0 + rg) * E_Q + r15], accO[rg]);
        }
    }
}

// ---------------------------------------------------------------------------
// Workspace layout (20 MB used):
//   [0,   8 MB)  Aq : Q tables, [16*1024][512] i8
//   [8,  20 MB)  Kt : K tables, [16*1024][768] i8  ([ck|sk|-ck])
// d_out is zeroed inside build_tables (0xAA-poisoned before each replay) and
// accumulated via device-scope f32 atomicAdd (8 blocks per element).
// ---------------------------------------------------------------------------
extern "C" void kernel_launch(void* const* d_in, const int* in_sizes, int n_in,
                              void* d_out, int out_size, void* d_ws, size_t ws_size,
                              hipStream_t stream) {
    const float* Q = (const float*)d_in[0];
    const float* K = (const float*)d_in[1];
    const float* V = (const float*)d_in[2];
    float* out = (float*)d_out;

    int8_t* Aq = (int8_t*)d_ws;
    int8_t* Kt = (int8_t*)((char*)d_ws + (size_t)8 * 1024 * 1024);

    build_tables<<<dim3(NB * S_LEN / 16, 2), 256, 0, stream>>>(Q, K, Aq, Kt, out);
    qk_pv<<<dim3(S_LEN / 128, S_LEN / 256, NB), 512, 0, stream>>>(Aq, Kt, V, out);
}

// Round 8
// 132.663 us; speedup vs baseline: 1.4642x; 1.4642x over previous
//
#include <hip/hip_runtime.h>
#include <hip/hip_bf16.h>
#include <stdint.h>

// Problem constants (B=16, S=1024, E=8 qubits -> 2^8 = 256 amplitudes).
#define NB 16
#define S_LEN 1024
#define E_Q 8

typedef float v4f __attribute__((ext_vector_type(4)));
typedef short v8s __attribute__((ext_vector_type(8)));
typedef int   v4i __attribute__((ext_vector_type(4)));

// ---------------------------------------------------------------------------
// Kernel 1: per-token cos/sin feature tables, INT8 (scale 127).
//   L = sum_i x_i s_i,  phi = -0.5 L - 0.25 (L^2 - ||x||^2),  s_i=(-1)^{z_i}
// Q-table row (512 B): [round(127 cos phi) | round(127 sin phi)]
// K-table row (768 B): [127 cos | 127 sin | -127 cos]  (third window feeds
//   the Im chain: Im = cq.sk + sq.(-ck)).
// Gray-code walk of the low nibble: one fma per z.
// Side job: first 128 blocks of the which==0 half zero d_out (exactly
// 32768 float4 == 131072 floats).
// ---------------------------------------------------------------------------
__global__ __launch_bounds__(256) void build_tables(
    const float* __restrict__ Q, const float* __restrict__ K,
    int8_t* __restrict__ Aq, int8_t* __restrict__ Kt,
    float* __restrict__ out)
{
    const int which = blockIdx.y;
    const float* X = which ? K : Q;

    if (which == 0 && blockIdx.x < 128) {   // zero d_out: 128*256 float4
        float4 z; z.x = z.y = z.z = z.w = 0.f;
        ((float4*)out)[blockIdx.x * 256 + threadIdx.x] = z;
    }

    const int tok = blockIdx.x * 16 + (threadIdx.x >> 4);
    const int hi  = threadIdx.x & 15;     // z bits 4..7
    const int zb  = hi * 16;

    const float* x = X + tok * E_Q;
    float xv[E_Q]; float sq = 0.f;
#pragma unroll
    for (int i = 0; i < E_Q; ++i) { xv[i] = x[i]; sq += xv[i] * xv[i]; }
    const float qsq = 0.25f * sq;

    // L at z = zb: low 4 bits 0 (sign +), high bits from `hi`.
    float L = xv[0] + xv[1] + xv[2] + xv[3];
#pragma unroll
    for (int i = 4; i < 8; ++i) L += ((hi >> (i - 4)) & 1) ? -xv[i] : xv[i];

    __align__(16) int8_t cb[16];
    __align__(16) int8_t sb[16];

    {   // n = 0, gray = 0
        const float phi = fmaf(-0.25f, L * L, fmaf(-0.5f, L, qsq));
        float s, c; __sincosf(phi, &s, &c);
        cb[0] = (int8_t)__float2int_rn(127.f * c);
        sb[0] = (int8_t)__float2int_rn(127.f * s);
    }
#pragma unroll
    for (int n = 1; n < 16; ++n) {
        const int g  = n ^ (n >> 1);
        const int gp = (n - 1) ^ ((n - 1) >> 1);
        const int t  = __builtin_ctz(g ^ gp);        // constant-folds
        const float twox = 2.0f * xv[t];
        L = ((g >> t) & 1) ? (L - twox) : (L + twox);
        const float phi = fmaf(-0.25f, L * L, fmaf(-0.5f, L, qsq));
        float s, c; __sincosf(phi, &s, &c);
        cb[g] = (int8_t)__float2int_rn(127.f * c);
        sb[g] = (int8_t)__float2int_rn(127.f * s);
    }

    if (which == 0) {
        int8_t* dst = Aq + (size_t)tok * 512;
        *(uint4*)(dst + zb)       = *(const uint4*)cb;
        *(uint4*)(dst + 256 + zb) = *(const uint4*)sb;
    } else {
        __align__(16) int8_t nb[16];
#pragma unroll
        for (int i = 0; i < 16; ++i) nb[i] = (int8_t)(-cb[i]);
        int8_t* dst = Kt + (size_t)tok * 768;
        *(uint4*)(dst + zb)       = *(const uint4*)cb;
        *(uint4*)(dst + 256 + zb) = *(const uint4*)sb;
        *(uint4*)(dst + 512 + zb) = *(const uint4*)nb;
    }
}

// ---------------------------------------------------------------------------
// Kernel 2: fused QK fidelity GEMM (i8) + nonlinearity + MFMA PV + atomics.
// R6 structure (128x128 tile, 256 threads, 48 KB LDS) with the live-register
// set trimmed for 3 blocks/CU (__launch_bounds__(256,3) -> cap ~170 unified
// VGPR+AGPR; R7's (512,4) capped at 128 and spilled 600 MB of scratch):
//  - staging offsets collapsed algebraically: for f = p*256+tid,
//    (f>>3)&7 == (tid>>3)&7 (p*32 = 0 mod 8), so swizzle q is p-invariant
//    and goffA/goffK = base + p*const (2 regs instead of 6).
//  - V load deferred to the epilogue (4 regs freed through the K-loop;
//    latency hides under the 64-instr acc-conversion sequence).
// Per c-iter (c=0..3) stage three [128][128B] i8 tiles:
//   lA  <- Q-chunk c of [cq|sq]      (row stride 512)
//   lK0 <- K-chunk c of [ck|sk|-ck]  (row stride 768)  -> Re chain
//   lK1 <- K-chunk c+2               -> Im chain (cq.sk + sq.(-ck))
// MFMA with A=K-frag, B=Q-frag (C^T trick) -> packed b64 attn stores.
// attn = (Re^2+Im^2)*2^-15/127^4 - 1 -> bf16 LDS [128][136]; PV via bf16
// MFMA (V^T [16][136]); f32 atomicAdd into pre-zeroed d_out.
// ---------------------------------------------------------------------------
__global__ __launch_bounds__(256, 3) void qk_pv(
    const int8_t* __restrict__ Aq, const int8_t* __restrict__ Kt,
    const float* __restrict__ V, float* __restrict__ out)
{
    __shared__ __align__(16) char smem[49152];
    int8_t* lA  = (int8_t*)smem;                    // [128][128] i8 (Q side)
    int8_t* lK0 = (int8_t*)(smem + 16384);
    int8_t* lK1 = (int8_t*)(smem + 32768);
    // phase-2 aliases (valid after the post-K-loop barrier)
    uint16_t* lattn = (uint16_t*)smem;              // [128][136] bf16, rows=i
    uint16_t* lVt   = (uint16_t*)(smem + 34816);    // [16][136]  bf16 (V^T)

    const int jblk = blockIdx.x, iblk = blockIdx.y, b = blockIdx.z;
    const int tid  = threadIdx.x;
    const int lane = tid & 63, wv = tid >> 6;
    const int wKj = wv >> 1, wQi = wv & 1;          // wave quadrant (j, i)
    const int r15 = lane & 15, qq = lane >> 4;

    // Staging offsets (p-invariant swizzle, see header comment):
    const int qsw   = (tid & 7) ^ ((tid >> 3) & 7);
    const int baseA = (tid >> 3) * 512 + qsw * 16;
    const int baseK = (tid >> 3) * 768 + qsw * 16;
    const int lbase = wv * 1024;                     // wave-uniform LDS base

    const int8_t* gA = Aq + (size_t)(b * S_LEN + iblk * 128) * 512;
    const int8_t* gK = Kt + (size_t)(b * S_LEN + jblk * 128) * 768;

    v4i accRe[4][4], accIm[4][4];                    // [nj][mi]
#pragma unroll
    for (int nj = 0; nj < 4; ++nj)
#pragma unroll
        for (int mi = 0; mi < 4; ++mi) {
            accRe[nj][mi] = (v4i)0;
            accIm[nj][mi] = (v4i)0;
        }

    for (int c = 0; c < 4; ++c) {
        __syncthreads();                             // LDS safe to overwrite
        const int cbyte = c * 128;
#pragma unroll
        for (int p = 0; p < 4; ++p) {
            const int lo = p * 4096 + lbase;
            __builtin_amdgcn_global_load_lds(
                (const __attribute__((address_space(1))) void*)(gA + cbyte + baseA + p * 16384),
                (__attribute__((address_space(3))) void*)(lA + lo), 16, 0, 0);
            __builtin_amdgcn_global_load_lds(
                (const __attribute__((address_space(1))) void*)(gK + cbyte + baseK + p * 24576),
                (__attribute__((address_space(3))) void*)(lK0 + lo), 16, 0, 0);
            __builtin_amdgcn_global_load_lds(
                (const __attribute__((address_space(1))) void*)(gK + 256 + cbyte + baseK + p * 24576),
                (__attribute__((address_space(3))) void*)(lK1 + lo), 16, 0, 0);
        }
        __syncthreads();                             // drain staging

#pragma unroll
        for (int w = 0; w < 2; ++w) {
            v4i qF[4];                               // B-operand (Q side)
#pragma unroll
            for (int mi = 0; mi < 4; ++mi) {
                const int row = wQi * 64 + mi * 16 + r15;
                qF[mi] = *(const v4i*)&lA[row * 128 + (((w << 2) | qq) ^ (row & 7)) * 16];
            }
#pragma unroll
            for (int nj = 0; nj < 4; ++nj) {
                const int rk  = wKj * 64 + nj * 16 + r15;
                const int off = rk * 128 + (((w << 2) | qq) ^ (rk & 7)) * 16;
                const v4i k0 = *(const v4i*)&lK0[off];   // A-operand (K side)
                const v4i k1 = *(const v4i*)&lK1[off];
#pragma unroll
                for (int mi = 0; mi < 4; ++mi) {
                    accRe[nj][mi] = __builtin_amdgcn_mfma_i32_16x16x64_i8(k0, qF[mi], accRe[nj][mi], 0, 0, 0);
                    accIm[nj][mi] = __builtin_amdgcn_mfma_i32_16x16x64_i8(k1, qF[mi], accIm[nj][mi], 0, 0, 0);
                }
            }
        }
    }

    // ---- Epilogue: attn -> LDS bf16 [i][136+j]; V^T -> LDS bf16 [16][136] ----
    __syncthreads();                                 // all frag reads done

    // V tile load (deferred from K-loop; latency hides under the conversions)
    const float4 vreg = ((const float4*)(V + ((size_t)b * S_LEN + jblk * 128) * E_Q))[tid];

    const float sc2 = 3.0517578125e-05f / 260144641.0f;   // 2^-15 / 127^4
    // C^T layout: D row = j = wKj*64 + nj*16 + qq*4 + rg,  col = i = wQi*64
    // + mi*16 + r15.  4 consecutive j at fixed i -> one packed b64 store.
#pragma unroll
    for (int nj = 0; nj < 4; ++nj) {
#pragma unroll
        for (int mi = 0; mi < 4; ++mi) {
            uint64_t pk = 0;
#pragma unroll
            for (int rg = 0; rg < 4; ++rg) {
                const float rf  = (float)accRe[nj][mi][rg];
                const float imf = (float)accIm[nj][mi][rg];
                const float a   = fmaf(rf * rf + imf * imf, sc2, -1.0f);
                __hip_bfloat16 ab = __float2bfloat16(a);
                pk |= (uint64_t)(*(const uint16_t*)&ab) << (16 * rg);
            }
            const int i  = wQi * 64 + mi * 16 + r15;
            const int j0 = wKj * 64 + nj * 16 + qq * 4;
            *(uint64_t*)&lattn[i * 136 + j0] = pk;
        }
    }
    {   // V^T: lVt[e][j] = bf16(V[b][jblk*128+j][e]); rows 8..15 hold stale
        // staged i8 bytes (finite-or-NaN as bf16, confined to unused output
        // cols 8..15 which are masked at store).
        const int j = tid >> 1, eh = (tid & 1) * 4;
        const float vv[4] = {vreg.x, vreg.y, vreg.z, vreg.w};
#pragma unroll
        for (int c2 = 0; c2 < 4; ++c2) {
            __hip_bfloat16 vb = __float2bfloat16(vv[c2]);
            lVt[(eh + c2) * 136 + j] = *(const uint16_t*)&vb;
        }
    }
    __syncthreads();

    // ---- Phase 2: out-tile = attnTile[128x128] @ Vt^T via bf16 MFMA ----
    v8s bfr[4];
#pragma unroll
    for (int ks3 = 0; ks3 < 4; ++ks3)
        bfr[ks3] = *(const v8s*)&lVt[r15 * 136 + ks3 * 32 + qq * 8];

    float* outb = out + (((size_t)b << 10) + iblk * 128) * E_Q;
#pragma unroll
    for (int mt = 0; mt < 2; ++mt) {
        const int rowbase = (wv * 2 + mt) * 16;
        v4f accO = (v4f)0.f;
#pragma unroll
        for (int ks3 = 0; ks3 < 4; ++ks3) {
            const v8s af = *(const v8s*)&lattn[(rowbase + r15) * 136 + ks3 * 32 + qq * 8];
            accO = __builtin_amdgcn_mfma_f32_16x16x32_bf16(af, bfr[ks3], accO, 0, 0, 0);
        }
        if (r15 < E_Q) {
            const int i0 = rowbase + qq * 4;
#pragma unroll
            for (int rg = 0; rg < 4; ++rg)
                atomicAdd(&outb[(i0 + rg) * E_Q + r15], accO[rg]);
        }
    }
}

// ---------------------------------------------------------------------------
// Workspace layout (20 MB used):
//   [0,   8 MB)  Aq : Q tables, [16*1024][512] i8
//   [8,  20 MB)  Kt : K tables, [16*1024][768] i8  ([ck|sk|-ck])
// d_out is zeroed inside build_tables (0xAA-poisoned before each replay) and
// accumulated via device-scope f32 atomicAdd (8 blocks per element).
// ---------------------------------------------------------------------------
extern "C" void kernel_launch(void* const* d_in, const int* in_sizes, int n_in,
                              void* d_out, int out_size, void* d_ws, size_t ws_size,
                              hipStream_t stream) {
    const float* Q = (const float*)d_in[0];
    const float* K = (const float*)d_in[1];
    const float* V = (const float*)d_in[2];
    float* out = (float*)d_out;

    int8_t* Aq = (int8_t*)d_ws;
    int8_t* Kt = (int8_t*)((char*)d_ws + (size_t)8 * 1024 * 1024);

    build_tables<<<dim3(NB * S_LEN / 16, 2), 256, 0, stream>>>(Q, K, Aq, Kt, out);
    qk_pv<<<dim3(S_LEN / 128, S_LEN / 128, NB), 256, 0, stream>>>(Aq, Kt, V, out);
}

// Round 9
// 87.136 us; speedup vs baseline: 2.2293x; 1.5225x over previous
//
#include <hip/hip_runtime.h>
#include <hip/hip_bf16.h>
#include <stdint.h>

// Problem constants (B=16, S=1024, E=8 qubits -> 2^8 = 256 amplitudes).
#define NB 16
#define S_LEN 1024
#define E_Q 8

typedef float v4f __attribute__((ext_vector_type(4)));
typedef short v8s __attribute__((ext_vector_type(8)));
typedef int   v4i __attribute__((ext_vector_type(4)));

// ---------------------------------------------------------------------------
// Kernel 1: per-token cos/sin feature tables, INT8 (scale 127).
//   L = sum_i x_i s_i,  phi = -0.5 L - 0.25 (L^2 - ||x||^2),  s_i=(-1)^{z_i}
// Q-table row (512 B): [round(127 cos phi) | round(127 sin phi)]
// K-table row (768 B): [127 cos | 127 sin | -127 cos]  (third window feeds
//   the Im chain: Im = cq.sk + sq.(-ck)).
// Gray-code walk of the low nibble: one fma per z.
// Side job: first 128 blocks of the which==0 half zero d_out (exactly
// 32768 float4 == 131072 floats).
// ---------------------------------------------------------------------------
__global__ __launch_bounds__(256) void build_tables(
    const float* __restrict__ Q, const float* __restrict__ K,
    int8_t* __restrict__ Aq, int8_t* __restrict__ Kt,
    float* __restrict__ out)
{
    const int which = blockIdx.y;
    const float* X = which ? K : Q;

    if (which == 0 && blockIdx.x < 128) {   // zero d_out: 128*256 float4
        float4 z; z.x = z.y = z.z = z.w = 0.f;
        ((float4*)out)[blockIdx.x * 256 + threadIdx.x] = z;
    }

    const int tok = blockIdx.x * 16 + (threadIdx.x >> 4);
    const int hi  = threadIdx.x & 15;     // z bits 4..7
    const int zb  = hi * 16;

    const float* x = X + tok * E_Q;
    float xv[E_Q]; float sq = 0.f;
#pragma unroll
    for (int i = 0; i < E_Q; ++i) { xv[i] = x[i]; sq += xv[i] * xv[i]; }
    const float qsq = 0.25f * sq;

    // L at z = zb: low 4 bits 0 (sign +), high bits from `hi`.
    float L = xv[0] + xv[1] + xv[2] + xv[3];
#pragma unroll
    for (int i = 4; i < 8; ++i) L += ((hi >> (i - 4)) & 1) ? -xv[i] : xv[i];

    __align__(16) int8_t cb[16];
    __align__(16) int8_t sb[16];

    {   // n = 0, gray = 0
        const float phi = fmaf(-0.25f, L * L, fmaf(-0.5f, L, qsq));
        float s, c; __sincosf(phi, &s, &c);
        cb[0] = (int8_t)__float2int_rn(127.f * c);
        sb[0] = (int8_t)__float2int_rn(127.f * s);
    }
#pragma unroll
    for (int n = 1; n < 16; ++n) {
        const int g  = n ^ (n >> 1);
        const int gp = (n - 1) ^ ((n - 1) >> 1);
        const int t  = __builtin_ctz(g ^ gp);        // constant-folds
        const float twox = 2.0f * xv[t];
        L = ((g >> t) & 1) ? (L - twox) : (L + twox);
        const float phi = fmaf(-0.25f, L * L, fmaf(-0.5f, L, qsq));
        float s, c; __sincosf(phi, &s, &c);
        cb[g] = (int8_t)__float2int_rn(127.f * c);
        sb[g] = (int8_t)__float2int_rn(127.f * s);
    }

    if (which == 0) {
        int8_t* dst = Aq + (size_t)tok * 512;
        *(uint4*)(dst + zb)       = *(const uint4*)cb;
        *(uint4*)(dst + 256 + zb) = *(const uint4*)sb;
    } else {
        __align__(16) int8_t nb[16];
#pragma unroll
        for (int i = 0; i < 16; ++i) nb[i] = (int8_t)(-cb[i]);
        int8_t* dst = Kt + (size_t)tok * 768;
        *(uint4*)(dst + zb)       = *(const uint4*)cb;
        *(uint4*)(dst + 256 + zb) = *(const uint4*)sb;
        *(uint4*)(dst + 512 + zb) = *(const uint4*)nb;
    }
}

// ---------------------------------------------------------------------------
// Kernel 2: fused QK fidelity GEMM (i8) + nonlinearity + MFMA PV + atomics.
// R6 envelope: 128x128 tile, 256 threads, 48 KB LDS, __launch_bounds__(256,2)
// -> 256-reg unified cap, fits the ~176-reg live set (112 arch + 64 accum)
// with NO spills. (R7 (512,4)->128-cap and R8 (256,3)->170-cap both forced
// scratch spilling: 67-160 us. 2 blocks/CU is this structure's ceiling.)
// Kept from R8 (register-neutral): p-invariant staging offsets (for
// f = p*256+tid, (f>>3)&7 == (tid>>3)&7, so the swizzle is p-invariant and
// goff = base + p*const), deferred V load (epilogue, hides under acc
// conversion).
// Per c-iter (c=0..3) stage three [128][128B] i8 tiles:
//   lA  <- Q-chunk c of [cq|sq]      (row stride 512)
//   lK0 <- K-chunk c of [ck|sk|-ck]  (row stride 768)  -> Re chain
//   lK1 <- K-chunk c+2               -> Im chain (cq.sk + sq.(-ck))
// MFMA with A=K-frag, B=Q-frag (C^T trick) -> packed b64 attn stores.
// attn = (Re^2+Im^2)*2^-15/127^4 - 1 -> bf16 LDS [128][136]; PV via bf16
// MFMA (V^T [16][136]); f32 atomicAdd into pre-zeroed d_out.
// ---------------------------------------------------------------------------
__global__ __launch_bounds__(256, 2) void qk_pv(
    const int8_t* __restrict__ Aq, const int8_t* __restrict__ Kt,
    const float* __restrict__ V, float* __restrict__ out)
{
    __shared__ __align__(16) char smem[49152];
    int8_t* lA  = (int8_t*)smem;                    // [128][128] i8 (Q side)
    int8_t* lK0 = (int8_t*)(smem + 16384);
    int8_t* lK1 = (int8_t*)(smem + 32768);
    // phase-2 aliases (valid after the post-K-loop barrier)
    uint16_t* lattn = (uint16_t*)smem;              // [128][136] bf16, rows=i
    uint16_t* lVt   = (uint16_t*)(smem + 34816);    // [16][136]  bf16 (V^T)

    const int jblk = blockIdx.x, iblk = blockIdx.y, b = blockIdx.z;
    const int tid  = threadIdx.x;
    const int lane = tid & 63, wv = tid >> 6;
    const int wKj = wv >> 1, wQi = wv & 1;          // wave quadrant (j, i)
    const int r15 = lane & 15, qq = lane >> 4;

    // Staging offsets (p-invariant swizzle, see header comment):
    const int qsw   = (tid & 7) ^ ((tid >> 3) & 7);
    const int baseA = (tid >> 3) * 512 + qsw * 16;
    const int baseK = (tid >> 3) * 768 + qsw * 16;
    const int lbase = wv * 1024;                     // wave-uniform LDS base

    const int8_t* gA = Aq + (size_t)(b * S_LEN + iblk * 128) * 512;
    const int8_t* gK = Kt + (size_t)(b * S_LEN + jblk * 128) * 768;

    v4i accRe[4][4], accIm[4][4];                    // [nj][mi]
#pragma unroll
    for (int nj = 0; nj < 4; ++nj)
#pragma unroll
        for (int mi = 0; mi < 4; ++mi) {
            accRe[nj][mi] = (v4i)0;
            accIm[nj][mi] = (v4i)0;
        }

    for (int c = 0; c < 4; ++c) {
        __syncthreads();                             // LDS safe to overwrite
        const int cbyte = c * 128;
#pragma unroll
        for (int p = 0; p < 4; ++p) {
            const int lo = p * 4096 + lbase;
            __builtin_amdgcn_global_load_lds(
                (const __attribute__((address_space(1))) void*)(gA + cbyte + baseA + p * 16384),
                (__attribute__((address_space(3))) void*)(lA + lo), 16, 0, 0);
            __builtin_amdgcn_global_load_lds(
                (const __attribute__((address_space(1))) void*)(gK + cbyte + baseK + p * 24576),
                (__attribute__((address_space(3))) void*)(lK0 + lo), 16, 0, 0);
            __builtin_amdgcn_global_load_lds(
                (const __attribute__((address_space(1))) void*)(gK + 256 + cbyte + baseK + p * 24576),
                (__attribute__((address_space(3))) void*)(lK1 + lo), 16, 0, 0);
        }
        __syncthreads();                             // drain staging

#pragma unroll
        for (int w = 0; w < 2; ++w) {
            v4i qF[4];                               // B-operand (Q side)
#pragma unroll
            for (int mi = 0; mi < 4; ++mi) {
                const int row = wQi * 64 + mi * 16 + r15;
                qF[mi] = *(const v4i*)&lA[row * 128 + (((w << 2) | qq) ^ (row & 7)) * 16];
            }
#pragma unroll
            for (int nj = 0; nj < 4; ++nj) {
                const int rk  = wKj * 64 + nj * 16 + r15;
                const int off = rk * 128 + (((w << 2) | qq) ^ (rk & 7)) * 16;
                const v4i k0 = *(const v4i*)&lK0[off];   // A-operand (K side)
                const v4i k1 = *(const v4i*)&lK1[off];
#pragma unroll
                for (int mi = 0; mi < 4; ++mi) {
                    accRe[nj][mi] = __builtin_amdgcn_mfma_i32_16x16x64_i8(k0, qF[mi], accRe[nj][mi], 0, 0, 0);
                    accIm[nj][mi] = __builtin_amdgcn_mfma_i32_16x16x64_i8(k1, qF[mi], accIm[nj][mi], 0, 0, 0);
                }
            }
        }
    }

    // ---- Epilogue: attn -> LDS bf16 [i][136+j]; V^T -> LDS bf16 [16][136] ----
    __syncthreads();                                 // all frag reads done

    // V tile load (deferred from K-loop; latency hides under the conversions)
    const float4 vreg = ((const float4*)(V + ((size_t)b * S_LEN + jblk * 128) * E_Q))[tid];

    const float sc2 = 3.0517578125e-05f / 260144641.0f;   // 2^-15 / 127^4
    // C^T layout: D row = j = wKj*64 + nj*16 + qq*4 + rg,  col = i = wQi*64
    // + mi*16 + r15.  4 consecutive j at fixed i -> one packed b64 store.
#pragma unroll
    for (int nj = 0; nj < 4; ++nj) {
#pragma unroll
        for (int mi = 0; mi < 4; ++mi) {
            uint64_t pk = 0;
#pragma unroll
            for (int rg = 0; rg < 4; ++rg) {
                const float rf  = (float)accRe[nj][mi][rg];
                const float imf = (float)accIm[nj][mi][rg];
                const float a   = fmaf(rf * rf + imf * imf, sc2, -1.0f);
                __hip_bfloat16 ab = __float2bfloat16(a);
                pk |= (uint64_t)(*(const uint16_t*)&ab) << (16 * rg);
            }
            const int i  = wQi * 64 + mi * 16 + r15;
            const int j0 = wKj * 64 + nj * 16 + qq * 4;
            *(uint64_t*)&lattn[i * 136 + j0] = pk;
        }
    }
    {   // V^T: lVt[e][j] = bf16(V[b][jblk*128+j][e]); rows 8..15 hold stale
        // staged i8 bytes (finite as bf16, confined to unused output cols
        // 8..15 which are masked at store).
        const int j = tid >> 1, eh = (tid & 1) * 4;
        const float vv[4] = {vreg.x, vreg.y, vreg.z, vreg.w};
#pragma unroll
        for (int c2 = 0; c2 < 4; ++c2) {
            __hip_bfloat16 vb = __float2bfloat16(vv[c2]);
            lVt[(eh + c2) * 136 + j] = *(const uint16_t*)&vb;
        }
    }
    __syncthreads();

    // ---- Phase 2: out-tile = attnTile[128x128] @ Vt^T via bf16 MFMA ----
    v8s bfr[4];
#pragma unroll
    for (int ks3 = 0; ks3 < 4; ++ks3)
        bfr[ks3] = *(const v8s*)&lVt[r15 * 136 + ks3 * 32 + qq * 8];

    float* outb = out + (((size_t)b << 10) + iblk * 128) * E_Q;
#pragma unroll
    for (int mt = 0; mt < 2; ++mt) {
        const int rowbase = (wv * 2 + mt) * 16;
        v4f accO = (v4f)0.f;
#pragma unroll
        for (int ks3 = 0; ks3 < 4; ++ks3) {
            const v8s af = *(const v8s*)&lattn[(rowbase + r15) * 136 + ks3 * 32 + qq * 8];
            accO = __builtin_amdgcn_mfma_f32_16x16x32_bf16(af, bfr[ks3], accO, 0, 0, 0);
        }
        if (r15 < E_Q) {
            const int i0 = rowbase + qq * 4;
#pragma unroll
            for (int rg = 0; rg < 4; ++rg)
                atomicAdd(&outb[(i0 + rg) * E_Q + r15], accO[rg]);
        }
    }
}

// ---------------------------------------------------------------------------
// Workspace layout (20 MB used):
//   [0,   8 MB)  Aq : Q tables, [16*1024][512] i8
//   [8,  20 MB)  Kt : K tables, [16*1024][768] i8  ([ck|sk|-ck])
// d_out is zeroed inside build_tables (0xAA-poisoned before each replay) and
// accumulated via device-scope f32 atomicAdd (8 blocks per element).
// ---------------------------------------------------------------------------
extern "C" void kernel_launch(void* const* d_in, const int* in_sizes, int n_in,
                              void* d_out, int out_size, void* d_ws, size_t ws_size,
                              hipStream_t stream) {
    const float* Q = (const float*)d_in[0];
    const float* K = (const float*)d_in[1];
    const float* V = (const float*)d_in[2];
    float* out = (float*)d_out;

    int8_t* Aq = (int8_t*)d_ws;
    int8_t* Kt = (int8_t*)((char*)d_ws + (size_t)8 * 1024 * 1024);

    build_tables<<<dim3(NB * S_LEN / 16, 2), 256, 0, stream>>>(Q, K, Aq, Kt, out);
    qk_pv<<<dim3(S_LEN / 128, S_LEN / 128, NB), 256, 0, stream>>>(Aq, Kt, V, out);
}